// Round 1
// baseline (5913.756 us; speedup 1.0000x reference)
//
#include <hip/hip_runtime.h>
#include <hip/hip_bf16.h>
#include <stdint.h>

// SubLSTM: T=512, B=64, I=1024, H=1024, G=4096
// Strategy: fused persistent cooperative kernel.
//   preact[b,g] = [x_t | h] @ W_cat[g]^T + bias[g],  W_cat = [W_in ; W_rec], K=2048
//   256 blocks = 4 batch-groups(16) x 64 unit-groups(16). 512 thr = 8 waves:
//   wave = (gate_type gt in {in,out,z,f}) x (K-half kh). W_cat B-fragments live
//   in registers (32 x bf16x8 = 128 VGPR) for all 512 steps. c state in regs.
//   Per step: stage [x_t|h] 64KB LDS (XOR-swizzled) -> 32 MFMA/wave -> gate
//   exchange in LDS -> sigmoid/cell update -> write h (bf16 dbuf) + outs fp32
//   -> device-scope grid barrier.

#define T_STEPS 512
#define NBLK 256

typedef short bf16x8 __attribute__((ext_vector_type(8)));
typedef float f32x4 __attribute__((ext_vector_type(4)));

// ---- ws layout (bytes) ----
// x_bf  : 0         .. 67108864   (T*B*I bf16)
// wcat  : 67108864  .. 83886080   (G*2048 bf16)
// hbuf  : 83886080  .. 84148224   (2 * 64*1024 bf16)
// cnt   : 84148224  (4 B)
#define WS_XBF    0
#define WS_WCAT   67108864
#define WS_HBUF   83886080
#define WS_CNT    84148224
#define WS_NEEDED (84148224 + 128)

__device__ __forceinline__ ushort f2bf(float f) {
  uint32_t u = __float_as_uint(f);
  uint32_t r = (u + 0x7fffu + ((u >> 16) & 1u)) >> 16;
  return (ushort)r;
}

__global__ void cvt_bf16_kernel(const float* __restrict__ src,
                                ushort* __restrict__ dst, int n4) {
  int i = blockIdx.x * 256 + threadIdx.x;
  if (i >= n4) return;
  float4 v = ((const float4*)src)[i];
  ushort4 o;
  o.x = f2bf(v.x); o.y = f2bf(v.y); o.z = f2bf(v.z); o.w = f2bf(v.w);
  ((ushort4*)dst)[i] = o;
}

// W_cat[g][0:1024] = W_in[g][:], W_cat[g][1024:2048] = W_rec[g][:]
__global__ void build_wcat_kernel(const float* __restrict__ w_in,
                                  const float* __restrict__ w_rec,
                                  ushort* __restrict__ wc) {
  int i = blockIdx.x * 256 + threadIdx.x;  // over groups of 4 elems
  if (i >= (4096 * 2048) / 4) return;
  int col4 = i & 511;
  int g = i >> 9;
  const float* src = (col4 < 256) ? (w_in + (size_t)g * 1024 + col4 * 4)
                                  : (w_rec + (size_t)g * 1024 + (col4 - 256) * 4);
  float4 v = *(const float4*)src;
  ushort4 o;
  o.x = f2bf(v.x); o.y = f2bf(v.y); o.z = f2bf(v.z); o.w = f2bf(v.w);
  ((ushort4*)wc)[i] = o;
}

__launch_bounds__(512, 2)
__global__ void sublstm_main(const ushort* __restrict__ xb,
                             const ushort* __restrict__ wc,
                             ushort* __restrict__ hbuf,
                             const float* __restrict__ c0,
                             const float* __restrict__ bias,
                             float* __restrict__ out,
                             unsigned* __restrict__ cnt) {
  __shared__ unsigned char smem[65536];  // [kh][16 rows][2048B/row], swizzled
  float* smemF = (float*)smem;

  const int tid  = threadIdx.x;
  const int lane = tid & 63;
  const int wid  = tid >> 6;
  const int gt   = wid >> 1;   // gate type: 0=in 1=out 2=z 3=f
  const int kh   = wid & 1;    // K-half: 0 = x part, 1 = h part
  const int bid  = blockIdx.x;
  const int b0   = (bid & 3) * 16;   // batch group
  const int j0   = (bid >> 2) * 16;  // hidden-unit group

  // ---- persistent B-fragments: W_cat rows gt*1024+j0+(lane&15), K-half kh ----
  bf16x8 bfrag[32];
  {
    const int row_g = gt * 1024 + j0 + (lane & 15);
    const ushort* wrow = wc + (size_t)row_g * 2048 + kh * 1024 + ((lane >> 4) * 8);
#pragma unroll
    for (int ks = 0; ks < 32; ++ks)
      bfrag[ks] = *(const bf16x8*)(wrow + ks * 32);
  }

  // ---- per-thread cell state + bias (threads 0..255: (batch bb, unit uu)) ----
  const int bb = tid >> 4, uu = tid & 15;
  float c_reg = 0.f;
  float bias_r0 = 0.f, bias_r1 = 0.f, bias_r2 = 0.f, bias_r3 = 0.f;
  if (tid < 256) {
    c_reg = c0[(size_t)(b0 + bb) * 1024 + j0 + uu];
    bias_r0 = bias[0 * 1024 + j0 + uu];
    bias_r1 = bias[1 * 1024 + j0 + uu];
    bias_r2 = bias[2 * 1024 + j0 + uu];
    bias_r3 = bias[3 * 1024 + j0 + uu];
  }

  // ---- A-read addressing (constant across steps except ks offset) ----
  const int arow = lane & 15;
  const int abase = kh * 32768 + arow * 2048 + ((lane >> 4) * 16);
  const int aswz = (arow & 7) << 4;

  for (int t = 0; t < T_STEPS; ++t) {
    const ushort* hprev = hbuf + (t & 1) * 65536;
    ushort* hnext = hbuf + ((t + 1) & 1) * 65536;

    // ---- stage [x_t | h] into LDS, XOR-swizzled (write side matches read) ----
    {
      const ushort* xrow = xb + ((size_t)t * 64 + b0) * 1024;
#pragma unroll
      for (int j = 0; j < 8; ++j) {
        int L = (tid + j * 512) * 16;          // linear byte in 64KB
        int row = (L >> 11) & 15;
        int colb = L & 2047;
        const ushort* src = (L >> 15)
            ? (hprev + (size_t)(b0 + row) * 1024 + (colb >> 1))
            : (xrow + (size_t)row * 1024 + (colb >> 1));
        uint4 v = *(const uint4*)src;
        *(uint4*)(smem + (L ^ ((row & 7) << 4))) = v;
      }
    }
    __syncthreads();

    // ---- MFMA: gates_partial[gt][kh] over K=1024, 2 acc chains ----
    f32x4 acc0 = {0.f, 0.f, 0.f, 0.f}, acc1 = {0.f, 0.f, 0.f, 0.f};
#pragma unroll
    for (int ks = 0; ks < 32; ks += 2) {
      bf16x8 a0 = *(const bf16x8*)(smem + ((abase + ks * 64) ^ aswz));
      bf16x8 a1 = *(const bf16x8*)(smem + ((abase + (ks + 1) * 64) ^ aswz));
      acc0 = __builtin_amdgcn_mfma_f32_16x16x32_bf16(a0, bfrag[ks], acc0, 0, 0, 0);
      acc1 = __builtin_amdgcn_mfma_f32_16x16x32_bf16(a1, bfrag[ks + 1], acc1, 0, 0, 0);
    }
    __syncthreads();  // all LDS A-reads done; safe to reuse smem

    // ---- exchange partial gates: smemF[wid*256 + b*16 + u] ----
#pragma unroll
    for (int r = 0; r < 4; ++r)
      smemF[wid * 256 + ((lane >> 4) * 4 + r) * 16 + (lane & 15)] = acc0[r] + acc1[r];
    __syncthreads();

    // ---- cell update (threads 0..255), write h/outs ----
    if (tid < 256) {
      float p_in  = smemF[0 * 256 + tid] + smemF[1 * 256 + tid] + bias_r0;
      float p_out = smemF[2 * 256 + tid] + smemF[3 * 256 + tid] + bias_r1;
      float p_z   = smemF[4 * 256 + tid] + smemF[5 * 256 + tid] + bias_r2;
      float p_f   = smemF[6 * 256 + tid] + smemF[7 * 256 + tid] + bias_r3;
      float g_in  = 1.f / (1.f + __expf(-p_in));
      float g_out = 1.f / (1.f + __expf(-p_out));
      float g_z   = 1.f / (1.f + __expf(-p_z));
      float g_f   = 1.f / (1.f + __expf(-p_f));
      c_reg = c_reg * g_f + g_z - g_in;
      float h_new = 1.f / (1.f + __expf(-c_reg)) - g_out;
      size_t oidx = (size_t)(b0 + bb) * 1024 + j0 + uu;
      out[(size_t)t * 65536 + oidx] = h_new;
      hnext[oidx] = f2bf(h_new);
      if (t == T_STEPS - 1) {
        out[(size_t)T_STEPS * 65536 + oidx] = h_new;           // hT
        out[(size_t)T_STEPS * 65536 + 65536 + oidx] = c_reg;   // cT
      }
    }

    // ---- device-scope grid barrier ----
    __syncthreads();  // drains this block's stores to its L2 (vmcnt before barrier)
    if (tid == 0) {
      // release: flushes XCD L2 (incl. other threads' stores, already in L2)
      __hip_atomic_fetch_add(cnt, 1u, __ATOMIC_RELEASE, __HIP_MEMORY_SCOPE_AGENT);
      unsigned tgt = (unsigned)(t + 1) * NBLK;
      while (__hip_atomic_load(cnt, __ATOMIC_RELAXED, __HIP_MEMORY_SCOPE_AGENT) < tgt) {
        __builtin_amdgcn_s_sleep(1);
      }
      // acquire: invalidate stale L1/L2 before any wave of this block reads h
      __builtin_amdgcn_fence(__ATOMIC_ACQUIRE, "agent");
    }
    __syncthreads();
  }
}

extern "C" void kernel_launch(void* const* d_in, const int* in_sizes, int n_in,
                              void* d_out, int out_size, void* d_ws, size_t ws_size,
                              hipStream_t stream) {
  const float* x     = (const float*)d_in[0];
  const float* h0    = (const float*)d_in[1];
  const float* c0    = (const float*)d_in[2];
  const float* w_in  = (const float*)d_in[3];
  const float* biasp = (const float*)d_in[4];
  const float* w_rec = (const float*)d_in[5];
  float* outp = (float*)d_out;

  if (ws_size < (size_t)WS_NEEDED) return;  // refuse to corrupt; will fail loudly

  uint8_t* ws = (uint8_t*)d_ws;
  ushort* xbp   = (ushort*)(ws + WS_XBF);
  ushort* wcp   = (ushort*)(ws + WS_WCAT);
  ushort* hbufp = (ushort*)(ws + WS_HBUF);
  unsigned* cntp = (unsigned*)(ws + WS_CNT);

  hipMemsetAsync(cntp, 0, 4, stream);
  // x -> bf16 (33.55M elems)
  cvt_bf16_kernel<<<32768, 256, 0, stream>>>(x, xbp, 8388608);
  // h0 -> bf16 into hbuf[0] (65536 elems)
  cvt_bf16_kernel<<<64, 256, 0, stream>>>(h0, hbufp, 16384);
  // W_cat build (8.39M elems)
  build_wcat_kernel<<<8192, 256, 0, stream>>>(w_in, w_rec, wcp);

  void* kargs[] = { (void*)&xbp, (void*)&wcp, (void*)&hbufp,
                    (void*)&c0,  (void*)&biasp, (void*)&outp, (void*)&cntp };
  hipLaunchCooperativeKernel((void*)sublstm_main, dim3(NBLK), dim3(512),
                             kargs, 0, stream);
}

// Round 2
// 2945.880 us; speedup vs baseline: 2.0075x; 2.0075x over previous
//
#include <hip/hip_runtime.h>
#include <hip/hip_bf16.h>
#include <stdint.h>

// SubLSTM: T=512, B=64, I=1024, H=1024, G=4096
// Persistent cooperative kernel, NO grid barrier:
//   h exchanged via self-validating 8B words: (2 x bf16) << 32 | step_tag,
//   relaxed agent-scope atomics (write-through to coherence point). Consumers
//   spin until tag == t. Flow control: block overwrites slot t&1 with h_{t+2}
//   only after consuming all of h_{t+1}, which implies every block in the
//   b-group finished reading h_t (data dependence through MFMA). No fences,
//   no L2 writeback/invalidate storms -> x and W_cat stay warm in L2.
// 256 blocks = 4 batch-groups(16) x 64 unit-groups(16), 512 thr = 8 waves:
//   wave = (gate gt) x (K-half kh); W_cat B-fragments persistent in registers.

#define T_STEPS 512
#define NBLK 256

typedef short bf16x8 __attribute__((ext_vector_type(8)));
typedef float f32x4 __attribute__((ext_vector_type(4)));

// ---- ws layout (bytes) ----
#define WS_XBF    0
#define WS_WCAT   67108864
#define WS_HBUF   83886080
#define WS_NEEDED (83886080 + 524288 + 256)

__device__ __forceinline__ ushort f2bf(float f) {
  uint32_t u = __float_as_uint(f);
  uint32_t r = (u + 0x7fffu + ((u >> 16) & 1u)) >> 16;
  return (ushort)r;
}

__global__ void cvt_bf16_kernel(const float* __restrict__ src,
                                ushort* __restrict__ dst, int n4) {
  int i = blockIdx.x * 256 + threadIdx.x;
  if (i >= n4) return;
  float4 v = ((const float4*)src)[i];
  ushort4 o;
  o.x = f2bf(v.x); o.y = f2bf(v.y); o.z = f2bf(v.z); o.w = f2bf(v.w);
  ((ushort4*)dst)[i] = o;
}

// W_cat[g][0:1024] = W_in[g][:], W_cat[g][1024:2048] = W_rec[g][:]
__global__ void build_wcat_kernel(const float* __restrict__ w_in,
                                  const float* __restrict__ w_rec,
                                  ushort* __restrict__ wc) {
  int i = blockIdx.x * 256 + threadIdx.x;
  if (i >= (4096 * 2048) / 4) return;
  int col4 = i & 511;
  int g = i >> 9;
  const float* src = (col4 < 256) ? (w_in + (size_t)g * 1024 + col4 * 4)
                                  : (w_rec + (size_t)g * 1024 + (col4 - 256) * 4);
  float4 v = *(const float4*)src;
  ushort4 o;
  o.x = f2bf(v.x); o.y = f2bf(v.y); o.z = f2bf(v.z); o.w = f2bf(v.w);
  ((ushort4*)wc)[i] = o;
}

// slot0 <- h0 with tag 0; slot1 <- poison tag 0xFFFFFFFF
__global__ void init_hbuf_kernel(const float* __restrict__ h0,
                                 unsigned long long* __restrict__ hb) {
  int i = blockIdx.x * 256 + threadIdx.x;  // 0..65535
  if (i >= 65536) return;
  if (i < 32768) {
    int row = i >> 9, u2 = i & 511;
    unsigned lo = f2bf(h0[(size_t)row * 1024 + u2 * 2]);
    unsigned hi = f2bf(h0[(size_t)row * 1024 + u2 * 2 + 1]);
    hb[i] = ((unsigned long long)((hi << 16) | lo) << 32) | 0ull;
  } else {
    hb[i] = 0xFFFFFFFFull;  // tag that never matches (tags used: 0..512)
  }
}

__launch_bounds__(512, 2)
__global__ void sublstm_main(const ushort* __restrict__ xb,
                             const ushort* __restrict__ wc,
                             unsigned long long* __restrict__ hb,
                             const float* __restrict__ c0,
                             const float* __restrict__ bias,
                             float* __restrict__ out) {
  extern __shared__ unsigned char smem[];      // [0,65536): A tiles, swizzled
  float* gsm = (float*)(smem + 65536);         // [65536,73728): gate partials

  const int tid  = threadIdx.x;
  const int lane = tid & 63;
  const int wid  = tid >> 6;
  const int gt   = wid >> 1;   // gate: 0=in 1=out 2=z 3=f
  const int kh   = wid & 1;    // K-half: 0 = x, 1 = h
  const int bid  = blockIdx.x;
  const int b0   = (bid & 3) * 16;
  const int j0   = (bid >> 2) * 16;

  // ---- persistent W_cat B-fragments (128 VGPRs) ----
  bf16x8 bfrag[32];
  {
    const int row_g = gt * 1024 + j0 + (lane & 15);
    const ushort* wrow = wc + (size_t)row_g * 2048 + kh * 1024 + ((lane >> 4) * 8);
#pragma unroll
    for (int ks = 0; ks < 32; ++ks)
      bfrag[ks] = *(const bf16x8*)(wrow + ks * 32);
  }

  // ---- cell state + bias (threads 0..255: (batch bb, unit uu)) ----
  const int bb = tid >> 4, uu = tid & 15;
  float c_reg = 0.f;
  float bias_r0 = 0.f, bias_r1 = 0.f, bias_r2 = 0.f, bias_r3 = 0.f;
  if (tid < 256) {
    c_reg = c0[(size_t)(b0 + bb) * 1024 + j0 + uu];
    bias_r0 = bias[0 * 1024 + j0 + uu];
    bias_r1 = bias[1 * 1024 + j0 + uu];
    bias_r2 = bias[2 * 1024 + j0 + uu];
    bias_r3 = bias[3 * 1024 + j0 + uu];
  }

  // ---- fixed addressing ----
  const int prow = tid >> 5;   // poll row 0..15
  const int pcol = tid & 31;   // poll col-lane
  const int arow = lane & 15;
  const int abase = kh * 32768 + arow * 2048 + ((lane >> 4) * 16);
  const int aswz = (arow & 7) << 4;
  const int pswz = (prow & 7) << 4;
  const int basew = (b0 + prow) * 512 + pcol;

  for (int t = 0; t < T_STEPS; ++t) {
    // ---- stage x half (plain cached loads; L2 stays warm) ----
    {
      const ushort* xrow = xb + ((size_t)t * 64 + b0) * 1024;
#pragma unroll
      for (int j = 0; j < 4; ++j) {
        int L = (tid + j * 512) * 16;            // 0..32767
        int row = L >> 11;
        int colb = L & 2047;
        uint4 v = *(const uint4*)(xrow + (size_t)row * 1024 + (colb >> 1));
        *(uint4*)(smem + (L ^ ((row & 7) << 4))) = v;
      }
    }

    // ---- poll h_t (self-validating words), stage into LDS ----
    {
      const int sb = (t & 1) << 15;
      unsigned long long v[16];
#pragma unroll
      for (int i = 0; i < 16; ++i)
        v[i] = __hip_atomic_load(&hb[sb + basew + i * 32],
                                 __ATOMIC_RELAXED, __HIP_MEMORY_SCOPE_AGENT);
#pragma unroll
      for (int i = 0; i < 16; ++i) {
        while ((unsigned)v[i] != (unsigned)t) {
          __builtin_amdgcn_s_sleep(1);
          v[i] = __hip_atomic_load(&hb[sb + basew + i * 32],
                                   __ATOMIC_RELAXED, __HIP_MEMORY_SCOPE_AGENT);
        }
      }
#pragma unroll
      for (int i = 0; i < 16; ++i) {
        int ba = 32768 + prow * 2048 + (pcol + i * 32) * 4;
        *(unsigned*)(smem + (ba ^ pswz)) = (unsigned)(v[i] >> 32);
      }
    }
    __syncthreads();   // syncA: tiles staged

    // ---- MFMA over K=1024 (this wave's K-half), 2 acc chains ----
    f32x4 acc0 = {0.f, 0.f, 0.f, 0.f}, acc1 = {0.f, 0.f, 0.f, 0.f};
#pragma unroll
    for (int ks = 0; ks < 32; ks += 2) {
      bf16x8 a0 = *(const bf16x8*)(smem + ((abase + ks * 64) ^ aswz));
      bf16x8 a1 = *(const bf16x8*)(smem + ((abase + (ks + 1) * 64) ^ aswz));
      acc0 = __builtin_amdgcn_mfma_f32_16x16x32_bf16(a0, bfrag[ks], acc0, 0, 0, 0);
      acc1 = __builtin_amdgcn_mfma_f32_16x16x32_bf16(a1, bfrag[ks + 1], acc1, 0, 0, 0);
    }

    // ---- gate partials -> dedicated LDS region ----
#pragma unroll
    for (int r = 0; r < 4; ++r)
      gsm[wid * 256 + ((lane >> 4) * 4 + r) * 16 + (lane & 15)] = acc0[r] + acc1[r];
    __syncthreads();   // syncB: MFMA reads + gate writes done

    // ---- cell update + publish h (threads 0..255) ----
    if (tid < 256) {
      float p_in  = gsm[0 * 256 + tid] + gsm[1 * 256 + tid] + bias_r0;
      float p_out = gsm[2 * 256 + tid] + gsm[3 * 256 + tid] + bias_r1;
      float p_z   = gsm[4 * 256 + tid] + gsm[5 * 256 + tid] + bias_r2;
      float p_f   = gsm[6 * 256 + tid] + gsm[7 * 256 + tid] + bias_r3;
      float g_in  = 1.f / (1.f + __expf(-p_in));
      float g_out = 1.f / (1.f + __expf(-p_out));
      float g_z   = 1.f / (1.f + __expf(-p_z));
      float g_f   = 1.f / (1.f + __expf(-p_f));
      c_reg = c_reg * g_f + g_z - g_in;
      float h_new = 1.f / (1.f + __expf(-c_reg)) - g_out;
      size_t oidx = (size_t)(b0 + bb) * 1024 + j0 + uu;
      out[(size_t)t * 65536 + oidx] = h_new;

      unsigned hbits = (unsigned)f2bf(h_new);
      unsigned pv = (unsigned)__shfl_xor((int)hbits, 1);
      if ((uu & 1) == 0) {
        unsigned hi32 = (pv << 16) | hbits;
        int wi = ((1 - (t & 1)) << 15) + (b0 + bb) * 512 + ((j0 + uu) >> 1);
        __hip_atomic_store(&hb[wi],
                           ((unsigned long long)hi32 << 32) |
                               (unsigned long long)(unsigned)(t + 1),
                           __ATOMIC_RELAXED, __HIP_MEMORY_SCOPE_AGENT);
      }
      if (t == T_STEPS - 1) {
        out[(size_t)T_STEPS * 65536 + oidx] = h_new;           // hT
        out[(size_t)T_STEPS * 65536 + 65536 + oidx] = c_reg;   // cT
      }
    }
    // no loop-end barrier: next staging only touches the A region (all MFMA
    // reads completed before syncB); gsm reads race nothing until next syncA.
  }
}

extern "C" void kernel_launch(void* const* d_in, const int* in_sizes, int n_in,
                              void* d_out, int out_size, void* d_ws, size_t ws_size,
                              hipStream_t stream) {
  const float* x     = (const float*)d_in[0];
  const float* h0    = (const float*)d_in[1];
  const float* c0    = (const float*)d_in[2];
  const float* w_in  = (const float*)d_in[3];
  const float* biasp = (const float*)d_in[4];
  const float* w_rec = (const float*)d_in[5];
  float* outp = (float*)d_out;

  if (ws_size < (size_t)WS_NEEDED) return;

  uint8_t* ws = (uint8_t*)d_ws;
  ushort* xbp = (ushort*)(ws + WS_XBF);
  ushort* wcp = (ushort*)(ws + WS_WCAT);
  unsigned long long* hbp = (unsigned long long*)(ws + WS_HBUF);

  hipFuncSetAttribute(reinterpret_cast<const void*>(sublstm_main),
                      hipFuncAttributeMaxDynamicSharedMemorySize, 73728);

  cvt_bf16_kernel<<<32768, 256, 0, stream>>>(x, xbp, 8388608);
  build_wcat_kernel<<<8192, 256, 0, stream>>>(w_in, w_rec, wcp);
  init_hbuf_kernel<<<256, 256, 0, stream>>>(h0, hbp);

  void* kargs[] = { (void*)&xbp, (void*)&wcp, (void*)&hbp,
                    (void*)&c0,  (void*)&biasp, (void*)&outp };
  hipLaunchCooperativeKernel((void*)sublstm_main, dim3(NBLK), dim3(512),
                             kargs, 73728, stream);
}

// Round 3
// 2330.067 us; speedup vs baseline: 2.5380x; 1.2643x over previous
//
#include <hip/hip_runtime.h>
#include <hip/hip_bf16.h>
#include <stdint.h>

// SubLSTM: T=512, B=64, I=1024, H=1024, G=4096
// Persistent cooperative kernel, barrier-free h exchange:
//   h words: (2 x bf16) << 32 | step_tag, relaxed agent-scope atomics.
//   Round-3 changes vs round-2:
//     (a) BATCH re-poll: each spin iteration reloads ALL pending words in
//         flight together (round-2 spun word-by-word -> up to 16 serial L3
//         round-trips per step; this was the dominant cost).
//     (b) x_t staged into double-buffered LDS at the END of step t-1,
//         overlapped with cell-update/publish -> off the critical path.
//     (c) 4 independent MFMA accumulator chains (dep depth 8, was 16).
// 256 blocks = 4 batch-groups(16) x 64 unit-groups(16), 512 thr = 8 waves:
//   wave = (gate gt) x (K-half kh); W_cat B-fragments persistent in registers.

#define T_STEPS 512
#define NBLK 256

typedef short bf16x8 __attribute__((ext_vector_type(8)));
typedef float f32x4 __attribute__((ext_vector_type(4)));

// ---- ws layout (bytes) ----
#define WS_XBF    0
#define WS_WCAT   67108864
#define WS_HBUF   83886080
#define WS_NEEDED (83886080 + 524288 + 256)

// ---- LDS layout (bytes) ----
//   [0, 65536)      : x tiles, double-buffered 2 x 32KB, XOR-swizzled
//   [65536, 98304)  : h tile, 32KB, XOR-swizzled
//   [98304, 106496) : gate partials, 8KB
#define LDS_X0   0
#define LDS_H    65536
#define LDS_G    98304
#define LDS_SIZE 106496

__device__ __forceinline__ ushort f2bf(float f) {
  uint32_t u = __float_as_uint(f);
  uint32_t r = (u + 0x7fffu + ((u >> 16) & 1u)) >> 16;
  return (ushort)r;
}

__global__ void cvt_bf16_kernel(const float* __restrict__ src,
                                ushort* __restrict__ dst, int n4) {
  int i = blockIdx.x * 256 + threadIdx.x;
  if (i >= n4) return;
  float4 v = ((const float4*)src)[i];
  ushort4 o;
  o.x = f2bf(v.x); o.y = f2bf(v.y); o.z = f2bf(v.z); o.w = f2bf(v.w);
  ((ushort4*)dst)[i] = o;
}

// W_cat[g][0:1024] = W_in[g][:], W_cat[g][1024:2048] = W_rec[g][:]
__global__ void build_wcat_kernel(const float* __restrict__ w_in,
                                  const float* __restrict__ w_rec,
                                  ushort* __restrict__ wc) {
  int i = blockIdx.x * 256 + threadIdx.x;
  if (i >= (4096 * 2048) / 4) return;
  int col4 = i & 511;
  int g = i >> 9;
  const float* src = (col4 < 256) ? (w_in + (size_t)g * 1024 + col4 * 4)
                                  : (w_rec + (size_t)g * 1024 + (col4 - 256) * 4);
  float4 v = *(const float4*)src;
  ushort4 o;
  o.x = f2bf(v.x); o.y = f2bf(v.y); o.z = f2bf(v.z); o.w = f2bf(v.w);
  ((ushort4*)wc)[i] = o;
}

// slot0 <- h0 with tag 0; slot1 <- poison tag 0xFFFFFFFF
__global__ void init_hbuf_kernel(const float* __restrict__ h0,
                                 unsigned long long* __restrict__ hb) {
  int i = blockIdx.x * 256 + threadIdx.x;  // 0..65535
  if (i >= 65536) return;
  if (i < 32768) {
    int row = i >> 9, u2 = i & 511;
    unsigned lo = f2bf(h0[(size_t)row * 1024 + u2 * 2]);
    unsigned hi = f2bf(h0[(size_t)row * 1024 + u2 * 2 + 1]);
    hb[i] = ((unsigned long long)((hi << 16) | lo) << 32) | 0ull;
  } else {
    hb[i] = 0xFFFFFFFFull;  // tag never matches (tags used: 0..512)
  }
}

__launch_bounds__(512, 2)
__global__ void sublstm_main(const ushort* __restrict__ xb,
                             const ushort* __restrict__ wc,
                             unsigned long long* __restrict__ hb,
                             const float* __restrict__ c0,
                             const float* __restrict__ bias,
                             float* __restrict__ out) {
  extern __shared__ unsigned char smem[];
  float* gsm = (float*)(smem + LDS_G);

  const int tid  = threadIdx.x;
  const int lane = tid & 63;
  const int wid  = tid >> 6;
  const int gt   = wid >> 1;   // gate: 0=in 1=out 2=z 3=f
  const int kh   = wid & 1;    // K-half: 0 = x, 1 = h
  const int bid  = blockIdx.x;
  const int b0   = (bid & 3) * 16;
  const int j0   = (bid >> 2) * 16;

  // ---- persistent W_cat B-fragments (128 VGPRs) ----
  bf16x8 bfrag[32];
  {
    const int row_g = gt * 1024 + j0 + (lane & 15);
    const ushort* wrow = wc + (size_t)row_g * 2048 + kh * 1024 + ((lane >> 4) * 8);
#pragma unroll
    for (int ks = 0; ks < 32; ++ks)
      bfrag[ks] = *(const bf16x8*)(wrow + ks * 32);
  }

  // ---- cell state + bias (threads 0..255: (batch bb, unit uu)) ----
  const int bb = tid >> 4, uu = tid & 15;
  float c_reg = 0.f;
  float bias_r0 = 0.f, bias_r1 = 0.f, bias_r2 = 0.f, bias_r3 = 0.f;
  if (tid < 256) {
    c_reg = c0[(size_t)(b0 + bb) * 1024 + j0 + uu];
    bias_r0 = bias[0 * 1024 + j0 + uu];
    bias_r1 = bias[1 * 1024 + j0 + uu];
    bias_r2 = bias[2 * 1024 + j0 + uu];
    bias_r3 = bias[3 * 1024 + j0 + uu];
  }

  // ---- fixed addressing ----
  const int prow = tid >> 5;       // h-poll row 0..15
  const int pcol = tid & 31;       // h-poll col-lane
  const int arow = lane & 15;
  const int aoff = arow * 2048 + ((lane >> 4) * 16);
  const int aswz = (arow & 7) << 4;
  const int pswz = (prow & 7) << 4;
  const int basew = (b0 + prow) * 512 + pcol;

  // ---- prologue: stage x_0 into buffer 0 ----
  {
    const ushort* xrow = xb + (size_t)b0 * 1024;
#pragma unroll
    for (int j = 0; j < 4; ++j) {
      int L = (tid + j * 512) * 16;            // 0..32767
      int row = L >> 11;
      int colb = L & 2047;
      uint4 v = *(const uint4*)(xrow + (size_t)row * 1024 + (colb >> 1));
      *(uint4*)(smem + (L ^ ((row & 7) << 4))) = v;
    }
  }

  for (int t = 0; t < T_STEPS; ++t) {
    // ---- poll h_t: batched re-poll of pending words only ----
    {
      const int sb = (t & 1) << 15;
      unsigned long long v[16];
#pragma unroll
      for (int i = 0; i < 16; ++i)
        v[i] = __hip_atomic_load(&hb[sb + basew + i * 32],
                                 __ATOMIC_RELAXED, __HIP_MEMORY_SCOPE_AGENT);
      for (;;) {
        unsigned np = 0;
#pragma unroll
        for (int i = 0; i < 16; ++i)
          if ((unsigned)v[i] != (unsigned)t) np |= (1u << i);
        if (!np) break;
        __builtin_amdgcn_s_sleep(1);
#pragma unroll
        for (int i = 0; i < 16; ++i)
          if (np & (1u << i))
            v[i] = __hip_atomic_load(&hb[sb + basew + i * 32],
                                     __ATOMIC_RELAXED, __HIP_MEMORY_SCOPE_AGENT);
      }
#pragma unroll
      for (int i = 0; i < 16; ++i) {
        int ba = prow * 2048 + (pcol + i * 32) * 4;
        *(unsigned*)(smem + LDS_H + (ba ^ pswz)) = (unsigned)(v[i] >> 32);
      }
    }
    __syncthreads();   // syncA: h staged (and x staged last step / prologue)

    // ---- MFMA over this wave's K-half, 4 independent acc chains ----
    const int abase = (kh ? LDS_H : LDS_X0 + ((t & 1) << 15)) + aoff;
    f32x4 acc0 = {0.f, 0.f, 0.f, 0.f}, acc1 = {0.f, 0.f, 0.f, 0.f};
    f32x4 acc2 = {0.f, 0.f, 0.f, 0.f}, acc3 = {0.f, 0.f, 0.f, 0.f};
#pragma unroll
    for (int ks = 0; ks < 32; ks += 4) {
      bf16x8 a0 = *(const bf16x8*)(smem + ((abase + (ks + 0) * 64) ^ aswz));
      bf16x8 a1 = *(const bf16x8*)(smem + ((abase + (ks + 1) * 64) ^ aswz));
      bf16x8 a2 = *(const bf16x8*)(smem + ((abase + (ks + 2) * 64) ^ aswz));
      bf16x8 a3 = *(const bf16x8*)(smem + ((abase + (ks + 3) * 64) ^ aswz));
      acc0 = __builtin_amdgcn_mfma_f32_16x16x32_bf16(a0, bfrag[ks + 0], acc0, 0, 0, 0);
      acc1 = __builtin_amdgcn_mfma_f32_16x16x32_bf16(a1, bfrag[ks + 1], acc1, 0, 0, 0);
      acc2 = __builtin_amdgcn_mfma_f32_16x16x32_bf16(a2, bfrag[ks + 2], acc2, 0, 0, 0);
      acc3 = __builtin_amdgcn_mfma_f32_16x16x32_bf16(a3, bfrag[ks + 3], acc3, 0, 0, 0);
    }

    // ---- gate partials -> LDS ----
#pragma unroll
    for (int r = 0; r < 4; ++r)
      gsm[wid * 256 + ((lane >> 4) * 4 + r) * 16 + (lane & 15)] =
          (acc0[r] + acc1[r]) + (acc2[r] + acc3[r]);
    __syncthreads();   // syncB: MFMA LDS reads + gate writes done

    // ---- cell update + publish h (threads 0..255) ----
    if (tid < 256) {
      float p_in  = gsm[0 * 256 + tid] + gsm[1 * 256 + tid] + bias_r0;
      float p_out = gsm[2 * 256 + tid] + gsm[3 * 256 + tid] + bias_r1;
      float p_z   = gsm[4 * 256 + tid] + gsm[5 * 256 + tid] + bias_r2;
      float p_f   = gsm[6 * 256 + tid] + gsm[7 * 256 + tid] + bias_r3;
      float g_in  = 1.f / (1.f + __expf(-p_in));
      float g_out = 1.f / (1.f + __expf(-p_out));
      float g_z   = 1.f / (1.f + __expf(-p_z));
      float g_f   = 1.f / (1.f + __expf(-p_f));
      c_reg = c_reg * g_f + g_z - g_in;
      float h_new = 1.f / (1.f + __expf(-c_reg)) - g_out;
      size_t oidx = (size_t)(b0 + bb) * 1024 + j0 + uu;
      out[(size_t)t * 65536 + oidx] = h_new;

      unsigned hbits = (unsigned)f2bf(h_new);
      unsigned pv = (unsigned)__shfl_xor((int)hbits, 1);
      if ((uu & 1) == 0) {
        unsigned hi32 = (pv << 16) | hbits;
        int wi = ((1 - (t & 1)) << 15) + (b0 + bb) * 512 + ((j0 + uu) >> 1);
        __hip_atomic_store(&hb[wi],
                           ((unsigned long long)hi32 << 32) |
                               (unsigned long long)(unsigned)(t + 1),
                           __ATOMIC_RELAXED, __HIP_MEMORY_SCOPE_AGENT);
      }
      if (t == T_STEPS - 1) {
        out[(size_t)T_STEPS * 65536 + oidx] = h_new;           // hT
        out[(size_t)T_STEPS * 65536 + 65536 + oidx] = c_reg;   // cT
      }
    }

    // ---- stage x_{t+1} into buffer (t+1)&1 (off critical path; writes
    //      protected from next step's reads by syncA(t+1)) ----
    if (t + 1 < T_STEPS) {
      const ushort* xrow = xb + ((size_t)(t + 1) * 64 + b0) * 1024;
      const int xo = ((t + 1) & 1) << 15;
#pragma unroll
      for (int j = 0; j < 4; ++j) {
        int L = (tid + j * 512) * 16;
        int row = L >> 11;
        int colb = L & 2047;
        uint4 v = *(const uint4*)(xrow + (size_t)row * 1024 + (colb >> 1));
        *(uint4*)(smem + xo + (L ^ ((row & 7) << 4))) = v;
      }
    }
    // no loop-end barrier needed: h/x staging writes of t+1 only touch
    // regions whose step-t reads completed before syncB(t); gsm reads of
    // step t complete before this thread reaches syncA(t+1).
  }
}

extern "C" void kernel_launch(void* const* d_in, const int* in_sizes, int n_in,
                              void* d_out, int out_size, void* d_ws, size_t ws_size,
                              hipStream_t stream) {
  const float* x     = (const float*)d_in[0];
  const float* h0    = (const float*)d_in[1];
  const float* c0    = (const float*)d_in[2];
  const float* w_in  = (const float*)d_in[3];
  const float* biasp = (const float*)d_in[4];
  const float* w_rec = (const float*)d_in[5];
  float* outp = (float*)d_out;

  if (ws_size < (size_t)WS_NEEDED) return;

  uint8_t* ws = (uint8_t*)d_ws;
  ushort* xbp = (ushort*)(ws + WS_XBF);
  ushort* wcp = (ushort*)(ws + WS_WCAT);
  unsigned long long* hbp = (unsigned long long*)(ws + WS_HBUF);

  hipFuncSetAttribute(reinterpret_cast<const void*>(sublstm_main),
                      hipFuncAttributeMaxDynamicSharedMemorySize, LDS_SIZE);

  cvt_bf16_kernel<<<32768, 256, 0, stream>>>(x, xbp, 8388608);
  build_wcat_kernel<<<8192, 256, 0, stream>>>(w_in, w_rec, wcp);
  init_hbuf_kernel<<<256, 256, 0, stream>>>(h0, hbp);

  void* kargs[] = { (void*)&xbp, (void*)&wcp, (void*)&hbp,
                    (void*)&c0,  (void*)&biasp, (void*)&outp };
  hipLaunchCooperativeKernel((void*)sublstm_main, dim3(NBLK), dim3(512),
                             kargs, LDS_SIZE, stream);
}

// Round 4
// 1524.190 us; speedup vs baseline: 3.8799x; 1.5287x over previous
//
#include <hip/hip_runtime.h>
#include <hip/hip_bf16.h>
#include <stdint.h>

// SubLSTM: T=512, B=64, I=1024, H=1024, G=4096
// Persistent cooperative kernel, barrier-free h exchange via self-validating
// 8B words ((2 x bf16)<<32 | step_tag) at agent scope.
// Round-4 changes vs round-3:
//   (a) poll loads are 16B global_load_dwordx4 sc0 sc1 (2 tagged words per
//       request): 8 requests/thread (was 16), half the poll VALU.
//   (b) h LDS staging as 8 x uint2 (was 16 x u32).
//   (c) publish-first epilogue; sigmoid = v_exp2 + v_rcp (no libm divide).
// 256 blocks = 4 batch-groups(16) x 64 unit-groups(16), 512 thr = 8 waves:
//   wave = (gate gt) x (K-half kh); W_cat fragments persistent in registers.

#define T_STEPS 512
#define NBLK 256

typedef short bf16x8 __attribute__((ext_vector_type(8)));
typedef float f32x4 __attribute__((ext_vector_type(4)));
typedef unsigned int u32x4 __attribute__((ext_vector_type(4)));

// ---- ws layout (bytes) ----
#define WS_XBF    0
#define WS_WCAT   67108864
#define WS_HBUF   83886080
#define WS_NEEDED (83886080 + 524288 + 256)

// ---- LDS layout (bytes) ----
#define LDS_X0   0          // x tiles, 2 x 32KB double buffer, swizzled
#define LDS_H    65536      // h tile, 32KB, swizzled
#define LDS_G    98304      // gate partials, 8KB
#define LDS_SIZE 106496

__device__ __forceinline__ ushort f2bf(float f) {
  uint32_t u = __float_as_uint(f);
  uint32_t r = (u + 0x7fffu + ((u >> 16) & 1u)) >> 16;
  return (ushort)r;
}

__device__ __forceinline__ float sigmoid_f(float x) {
  float e = __builtin_amdgcn_exp2f(-1.44269504f * x);
  return __builtin_amdgcn_rcpf(1.0f + e);
}

// 16B load bypassing L1+L2 (reads the coherence point / MALL).
__device__ __forceinline__ u32x4 poll_load16(const unsigned long long* p) {
  u32x4 v;
  asm volatile("global_load_dwordx4 %0, %1, off sc0 sc1"
               : "=v"(v) : "v"(p));
  return v;
}
#define POLL_FENCE() do {                          \
    asm volatile("s_waitcnt vmcnt(0)" ::: "memory"); \
    __builtin_amdgcn_sched_barrier(0);             \
  } while (0)

__global__ void cvt_bf16_kernel(const float* __restrict__ src,
                                ushort* __restrict__ dst, int n4) {
  int i = blockIdx.x * 256 + threadIdx.x;
  if (i >= n4) return;
  float4 v = ((const float4*)src)[i];
  ushort4 o;
  o.x = f2bf(v.x); o.y = f2bf(v.y); o.z = f2bf(v.z); o.w = f2bf(v.w);
  ((ushort4*)dst)[i] = o;
}

// W_cat[g][0:1024] = W_in[g][:], W_cat[g][1024:2048] = W_rec[g][:]
__global__ void build_wcat_kernel(const float* __restrict__ w_in,
                                  const float* __restrict__ w_rec,
                                  ushort* __restrict__ wc) {
  int i = blockIdx.x * 256 + threadIdx.x;
  if (i >= (4096 * 2048) / 4) return;
  int col4 = i & 511;
  int g = i >> 9;
  const float* src = (col4 < 256) ? (w_in + (size_t)g * 1024 + col4 * 4)
                                  : (w_rec + (size_t)g * 1024 + (col4 - 256) * 4);
  float4 v = *(const float4*)src;
  ushort4 o;
  o.x = f2bf(v.x); o.y = f2bf(v.y); o.z = f2bf(v.z); o.w = f2bf(v.w);
  ((ushort4*)wc)[i] = o;
}

// slot0 <- h0 with tag 0; slot1 <- poison tag
__global__ void init_hbuf_kernel(const float* __restrict__ h0,
                                 unsigned long long* __restrict__ hb) {
  int i = blockIdx.x * 256 + threadIdx.x;  // 0..65535
  if (i >= 65536) return;
  if (i < 32768) {
    int row = i >> 9, u2 = i & 511;
    unsigned lo = f2bf(h0[(size_t)row * 1024 + u2 * 2]);
    unsigned hi = f2bf(h0[(size_t)row * 1024 + u2 * 2 + 1]);
    hb[i] = ((unsigned long long)((hi << 16) | lo) << 32) | 0ull;
  } else {
    hb[i] = 0xFFFFFFFFull;  // never matches (tags used: 0..512)
  }
}

__launch_bounds__(512, 2)
__global__ void sublstm_main(const ushort* __restrict__ xb,
                             const ushort* __restrict__ wc,
                             unsigned long long* __restrict__ hb,
                             const float* __restrict__ c0,
                             const float* __restrict__ bias,
                             float* __restrict__ out) {
  extern __shared__ unsigned char smem[];
  float* gsm = (float*)(smem + LDS_G);

  const int tid  = threadIdx.x;
  const int lane = tid & 63;
  const int wid  = tid >> 6;
  const int gt   = wid >> 1;   // gate: 0=in 1=out 2=z 3=f
  const int kh   = wid & 1;    // K-half: 0 = x, 1 = h
  const int bid  = blockIdx.x;
  const int b0   = (bid & 3) * 16;
  const int j0   = (bid >> 2) * 16;

  // ---- persistent W_cat B-fragments ----
  bf16x8 bfrag[32];
  {
    const int row_g = gt * 1024 + j0 + (lane & 15);
    const ushort* wrow = wc + (size_t)row_g * 2048 + kh * 1024 + ((lane >> 4) * 8);
#pragma unroll
    for (int ks = 0; ks < 32; ++ks)
      bfrag[ks] = *(const bf16x8*)(wrow + ks * 32);
  }

  // ---- cell state + bias (threads 0..255: (batch bb, unit uu)) ----
  const int bb = tid >> 4, uu = tid & 15;
  float c_reg = 0.f;
  float bias_r0 = 0.f, bias_r1 = 0.f, bias_r2 = 0.f, bias_r3 = 0.f;
  if (tid < 256) {
    c_reg = c0[(size_t)(b0 + bb) * 1024 + j0 + uu];
    bias_r0 = bias[0 * 1024 + j0 + uu];
    bias_r1 = bias[1 * 1024 + j0 + uu];
    bias_r2 = bias[2 * 1024 + j0 + uu];
    bias_r3 = bias[3 * 1024 + j0 + uu];
  }

  // ---- fixed addressing ----
  const int prow = tid >> 5;                 // h-poll row 0..15
  const int pc   = tid & 31;                 // h-poll chunk-lane 0..31
  const int arow = lane & 15;
  const int aoff = arow * 2048 + ((lane >> 4) * 16);
  const int aswz = (arow & 7) << 4;
  const int pswz = (prow & 7) << 4;
  const int basew2 = (b0 + prow) * 512 + pc * 2;   // word index (16B aligned)
  const int hbyte  = prow * 2048 + pc * 8;         // LDS byte base for staging

  // ---- prologue: stage x_0 into buffer 0 ----
  {
    const ushort* xrow = xb + (size_t)b0 * 1024;
#pragma unroll
    for (int j = 0; j < 4; ++j) {
      int L = (tid + j * 512) * 16;            // 0..32767
      int row = L >> 11;
      int colb = L & 2047;
      uint4 v = *(const uint4*)(xrow + (size_t)row * 1024 + (colb >> 1));
      *(uint4*)(smem + (L ^ ((row & 7) << 4))) = v;
    }
  }

  for (int t = 0; t < T_STEPS; ++t) {
    // ---- poll h_t: 8 x dwordx4, batched re-poll of pending chunks only ----
    {
      const unsigned long long* pb = hb + ((t & 1) << 15) + basew2;
      u32x4 vv[8];
#pragma unroll
      for (int i = 0; i < 8; ++i) vv[i] = poll_load16(pb + i * 64);
      POLL_FENCE();
      for (;;) {
        unsigned np = 0;
#pragma unroll
        for (int i = 0; i < 8; ++i)
          if ((vv[i].x != (unsigned)t) || (vv[i].z != (unsigned)t))
            np |= (1u << i);
        if (!np) break;
        __builtin_amdgcn_s_sleep(1);
#pragma unroll
        for (int i = 0; i < 8; ++i)
          if (np & (1u << i)) vv[i] = poll_load16(pb + i * 64);
        POLL_FENCE();
      }
      // stage data dwords (2 x bf16 each) -> swizzled LDS h tile
#pragma unroll
      for (int i = 0; i < 8; ++i) {
        uint2 d; d.x = vv[i].y; d.y = vv[i].w;
        *(uint2*)(smem + LDS_H + ((hbyte + i * 256) ^ pswz)) = d;
      }
    }
    __syncthreads();   // syncA: h staged (x staged last step / prologue)

    // ---- MFMA over this wave's K-half, 4 independent acc chains ----
    const int abase = (kh ? LDS_H : LDS_X0 + ((t & 1) << 15)) + aoff;
    f32x4 acc0 = {0.f, 0.f, 0.f, 0.f}, acc1 = {0.f, 0.f, 0.f, 0.f};
    f32x4 acc2 = {0.f, 0.f, 0.f, 0.f}, acc3 = {0.f, 0.f, 0.f, 0.f};
#pragma unroll
    for (int ks = 0; ks < 32; ks += 4) {
      bf16x8 a0 = *(const bf16x8*)(smem + ((abase + (ks + 0) * 64) ^ aswz));
      bf16x8 a1 = *(const bf16x8*)(smem + ((abase + (ks + 1) * 64) ^ aswz));
      bf16x8 a2 = *(const bf16x8*)(smem + ((abase + (ks + 2) * 64) ^ aswz));
      bf16x8 a3 = *(const bf16x8*)(smem + ((abase + (ks + 3) * 64) ^ aswz));
      acc0 = __builtin_amdgcn_mfma_f32_16x16x32_bf16(a0, bfrag[ks + 0], acc0, 0, 0, 0);
      acc1 = __builtin_amdgcn_mfma_f32_16x16x32_bf16(a1, bfrag[ks + 1], acc1, 0, 0, 0);
      acc2 = __builtin_amdgcn_mfma_f32_16x16x32_bf16(a2, bfrag[ks + 2], acc2, 0, 0, 0);
      acc3 = __builtin_amdgcn_mfma_f32_16x16x32_bf16(a3, bfrag[ks + 3], acc3, 0, 0, 0);
    }

    // ---- gate partials -> LDS ----
#pragma unroll
    for (int r = 0; r < 4; ++r)
      gsm[wid * 256 + ((lane >> 4) * 4 + r) * 16 + (lane & 15)] =
          (acc0[r] + acc1[r]) + (acc2[r] + acc3[r]);
    __syncthreads();   // syncB: MFMA LDS reads + gate writes done

    // ---- cell update; publish h FIRST, then out (threads 0..255) ----
    if (tid < 256) {
      float p_in  = gsm[0 * 256 + tid] + gsm[1 * 256 + tid] + bias_r0;
      float p_out = gsm[2 * 256 + tid] + gsm[3 * 256 + tid] + bias_r1;
      float p_z   = gsm[4 * 256 + tid] + gsm[5 * 256 + tid] + bias_r2;
      float p_f   = gsm[6 * 256 + tid] + gsm[7 * 256 + tid] + bias_r3;
      float g_in  = sigmoid_f(p_in);
      float g_out = sigmoid_f(p_out);
      float g_z   = sigmoid_f(p_z);
      float g_f   = sigmoid_f(p_f);
      c_reg = c_reg * g_f + g_z - g_in;
      float h_new = sigmoid_f(c_reg) - g_out;

      unsigned hbits = (unsigned)f2bf(h_new);
      unsigned pv = (unsigned)__shfl_xor((int)hbits, 1);
      if ((uu & 1) == 0) {
        unsigned hi32 = (pv << 16) | hbits;
        int wi = ((1 - (t & 1)) << 15) + (b0 + bb) * 512 + ((j0 + uu) >> 1);
        __hip_atomic_store(&hb[wi],
                           ((unsigned long long)hi32 << 32) |
                               (unsigned long long)(unsigned)(t + 1),
                           __ATOMIC_RELAXED, __HIP_MEMORY_SCOPE_AGENT);
      }
      size_t oidx = (size_t)(b0 + bb) * 1024 + j0 + uu;
      out[(size_t)t * 65536 + oidx] = h_new;
      if (t == T_STEPS - 1) {
        out[(size_t)T_STEPS * 65536 + oidx] = h_new;           // hT
        out[(size_t)T_STEPS * 65536 + 65536 + oidx] = c_reg;   // cT
      }
    }

    // ---- stage x_{t+1} (off critical path; protected by syncA(t+1)) ----
    if (t + 1 < T_STEPS) {
      const ushort* xrow = xb + ((size_t)(t + 1) * 64 + b0) * 1024;
      const int xo = ((t + 1) & 1) << 15;
#pragma unroll
      for (int j = 0; j < 4; ++j) {
        int L = (tid + j * 512) * 16;
        int row = L >> 11;
        int colb = L & 2047;
        uint4 v = *(const uint4*)(xrow + (size_t)row * 1024 + (colb >> 1));
        *(uint4*)(smem + xo + (L ^ ((row & 7) << 4))) = v;
      }
    }
    // no loop-end barrier: staging writes for t+1 only touch regions whose
    // step-t readers finished before syncB(t); gsm reads of step t complete
    // before this thread reaches syncA(t+1).
  }
}

extern "C" void kernel_launch(void* const* d_in, const int* in_sizes, int n_in,
                              void* d_out, int out_size, void* d_ws, size_t ws_size,
                              hipStream_t stream) {
  const float* x     = (const float*)d_in[0];
  const float* h0    = (const float*)d_in[1];
  const float* c0    = (const float*)d_in[2];
  const float* w_in  = (const float*)d_in[3];
  const float* biasp = (const float*)d_in[4];
  const float* w_rec = (const float*)d_in[5];
  float* outp = (float*)d_out;

  if (ws_size < (size_t)WS_NEEDED) return;

  uint8_t* ws = (uint8_t*)d_ws;
  ushort* xbp = (ushort*)(ws + WS_XBF);
  ushort* wcp = (ushort*)(ws + WS_WCAT);
  unsigned long long* hbp = (unsigned long long*)(ws + WS_HBUF);

  hipFuncSetAttribute(reinterpret_cast<const void*>(sublstm_main),
                      hipFuncAttributeMaxDynamicSharedMemorySize, LDS_SIZE);

  cvt_bf16_kernel<<<32768, 256, 0, stream>>>(x, xbp, 8388608);
  build_wcat_kernel<<<8192, 256, 0, stream>>>(w_in, w_rec, wcp);
  init_hbuf_kernel<<<256, 256, 0, stream>>>(h0, hbp);

  void* kargs[] = { (void*)&xbp, (void*)&wcp, (void*)&hbp,
                    (void*)&c0,  (void*)&biasp, (void*)&outp };
  hipLaunchCooperativeKernel((void*)sublstm_main, dim3(NBLK), dim3(512),
                             kargs, LDS_SIZE, stream);
}